// Round 4
// baseline (52.413 us; speedup 1.0000x reference)
//
#include <hip/hip_runtime.h>
#include <hip/hip_bf16.h>

// PseudoTripletLoss on MI355X (gfx950)
// loss = sum_{i<j} [ same(i,j) ? relu(1 - cos_ij) : relu(cos_ij - 0.1) ] / (n(n-1))
//
// K1: row-normalize fp32 embeddings -> bf16 `en` in d_ws (one wave per row)
// K2: WAVE-INDEPENDENT triangular tiling: each wave owns 4 consecutive 64x64
//     tiles of the strict upper triangle. No LDS, no barriers. A-strip (64 rows
//     x K=128) + row labels live in registers, reused across the wave's tiles;
//     B fragments register-prefetched from L2 before the current tile's
//     epilogue (~770 VALU cyc) which hides the L2 latency. Epilogue (hinge
//     loss) overlaps the other resident wave's MFMAs (separate pipes).
// K3: deterministic single-block reduction of per-wave partials -> d_out[0]

typedef __attribute__((ext_vector_type(8))) short short8;
typedef __attribute__((ext_vector_type(4))) float f32x4;

#define DIM 128
#define MARGIN 0.1f
#define TPW 4            // tiles per wave

static __device__ __forceinline__ unsigned short f2bf(float f) {
    unsigned int u = __builtin_bit_cast(unsigned int, f);
    u += 0x7FFFu + ((u >> 16) & 1u);   // round-to-nearest-even
    return (unsigned short)(u >> 16);
}

// ---------------- K1: normalize rows, write packed bf16 ----------------
__global__ void __launch_bounds__(256) norm_bf16_kernel(const float* __restrict__ e,
                                                        unsigned int* __restrict__ en_packed) {
    const int row  = blockIdx.x * 4 + (threadIdx.x >> 6);  // one wave per row
    const int lane = threadIdx.x & 63;
    const float2 v = *reinterpret_cast<const float2*>(e + row * DIM + lane * 2);
    float s = v.x * v.x + v.y * v.y;
    #pragma unroll
    for (int off = 32; off; off >>= 1) s += __shfl_xor(s, off, 64);
    const float scale = 1.0f / fmaxf(sqrtf(s), 1e-8f);
    const unsigned int lo = f2bf(v.x * scale);
    const unsigned int hi = f2bf(v.y * scale);
    en_packed[row * (DIM / 2) + lane] = (hi << 16) | lo;
}

// ---------------- K2: wave-independent 64x64 triangular tiles ----------------
__global__ void __launch_bounds__(256, 2)
tri_loss_kernel(const short* __restrict__ en, const int* __restrict__ labels,
                float* __restrict__ partials, int nt, int ntri) {
    const int lane = threadIdx.x & 63;
    const int wav  = blockIdx.x * 4 + (threadIdx.x >> 6);
    const int lm   = lane & 15;
    const int hi   = lane >> 4;

    const int t0 = wav * TPW;
    if (t0 >= ntri) { if (lane == 0) partials[wav] = 0.0f; return; }

    // ---- decode first tile (I,J), J >= I, row-major over strict-upper incl. diagonal tiles ----
    const float wf = (float)(2 * nt + 1);
    int I = (int)((wf - sqrtf(wf * wf - 8.0f * (float)t0)) * 0.5f);
    if (I < 0) I = 0;
    #pragma unroll 1
    while (I > 0 && (I * nt - (I * (I - 1)) / 2) > t0) --I;
    #pragma unroll 1
    while (((I + 1) * nt - ((I + 1) * I) / 2) <= t0) ++I;
    int J = I + (t0 - (I * nt - (I * (I - 1)) / 2));

    // ---- A strip (rows I*64..+64, full K=128) + row labels in registers ----
    short8 a[4][4];
    int4 li[4];
    #pragma unroll
    for (int m = 0; m < 4; ++m) {
        const short* pa = en + (size_t)(I * 64 + m * 16 + lm) * DIM + hi * 8;
        #pragma unroll
        for (int ks = 0; ks < 4; ++ks) a[m][ks] = *(const short8*)(pa + ks * 32);
        li[m] = *(const int4*)(labels + I * 64 + m * 16 + hi * 4);
    }

    // ---- first tile's B fragments + column labels ----
    short8 b[4][4];
    int labj[4];
    #pragma unroll
    for (int n = 0; n < 4; ++n) {
        const short* pb = en + (size_t)(J * 64 + n * 16 + lm) * DIM + hi * 8;
        #pragma unroll
        for (int ks = 0; ks < 4; ++ks) b[n][ks] = *(const short8*)(pb + ks * 32);
        labj[n] = labels[J * 64 + n * 16 + lm];
    }

    float lsum = 0.0f;
    const int rb = hi * 4;

    #pragma unroll
    for (int k = 0; k < TPW; ++k) {
        if (t0 + k >= ntri) break;                     // wave-uniform guard

        // ---- MFMA: 64x64 tile, K=128 ----
        f32x4 acc[4][4] = {};
        #pragma unroll
        for (int ks = 0; ks < 4; ++ks)
            #pragma unroll
            for (int m = 0; m < 4; ++m)
                #pragma unroll
                for (int n = 0; n < 4; ++n)
                    acc[m][n] = __builtin_amdgcn_mfma_f32_16x16x32_bf16(a[m][ks], b[n][ks], acc[m][n], 0, 0, 0);

        // ---- advance + prefetch next tile (B regs free after MFMA issue) ----
        const int Icur = I, Jcur = J;
        const int labj_cur0 = labj[0], labj_cur1 = labj[1], labj_cur2 = labj[2], labj_cur3 = labj[3];
        int Jn = J + 1, In = I;
        if (Jn == nt) { In = I + 1; Jn = In; }
        if (k + 1 < TPW && t0 + k + 1 < ntri) {
            if (In != I) {                              // strip change: reload A + row labels
                #pragma unroll
                for (int m = 0; m < 4; ++m) {
                    const short* pa = en + (size_t)(In * 64 + m * 16 + lm) * DIM + hi * 8;
                    #pragma unroll
                    for (int ks = 0; ks < 4; ++ks) a[m][ks] = *(const short8*)(pa + ks * 32);
                    li[m] = *(const int4*)(labels + In * 64 + m * 16 + hi * 4);
                }
            }
            #pragma unroll
            for (int n = 0; n < 4; ++n) {              // prefetch next B + labels
                const short* pb = en + (size_t)(Jn * 64 + n * 16 + lm) * DIM + hi * 8;
                #pragma unroll
                for (int ks = 0; ks < 4; ++ks) b[n][ks] = *(const short8*)(pb + ks * 32);
                labj[n] = labels[Jn * 64 + n * 16 + lm];
            }
        }
        I = In; J = Jn;

        // ---- epilogue on current tile (hides prefetch latency; overlaps other
        //      wave's MFMAs on this SIMD) ----
        const int lj[4] = {labj_cur0, labj_cur1, labj_cur2, labj_cur3};
        if (Icur == Jcur) {                             // diagonal tile: strict i<j
            #pragma unroll
            for (int m = 0; m < 4; ++m) {
                #pragma unroll
                for (int r = 0; r < 4; ++r) {
                    const int i   = Icur * 64 + m * 16 + rb + r;
                    const int l_i = ((const int*)&li[m])[r];
                    #pragma unroll
                    for (int n = 0; n < 4; ++n) {
                        const int j = Jcur * 64 + n * 16 + lm;
                        const float s  = acc[m][n][r];
                        const float t2 = (l_i == lj[n]) ? (1.0f - s) : (s - MARGIN);
                        if (i < j) lsum += fmaxf(t2, 0.0f);
                    }
                }
            }
        } else {                                        // off-diagonal: all pairs count
            #pragma unroll
            for (int m = 0; m < 4; ++m) {
                #pragma unroll
                for (int r = 0; r < 4; ++r) {
                    const int l_i = ((const int*)&li[m])[r];
                    #pragma unroll
                    for (int n = 0; n < 4; ++n) {
                        const float s  = acc[m][n][r];
                        const float t2 = (l_i == lj[n]) ? (1.0f - s) : (s - MARGIN);
                        lsum += fmaxf(t2, 0.0f);
                    }
                }
            }
        }
    }

    // ---- per-wave reduce, no cross-wave sync needed ----
    #pragma unroll
    for (int off = 32; off; off >>= 1) lsum += __shfl_down(lsum, off, 64);
    if (lane == 0) partials[wav] = lsum;
}

// ---------------- K3: final deterministic reduce ----------------
__global__ void __launch_bounds__(256) final_reduce_kernel(const float* __restrict__ partials,
                                                           float* __restrict__ out,
                                                           int n, float inv_denom) {
    float s = 0.0f;
    for (int i = threadIdx.x; i < n; i += 256) s += partials[i];
    #pragma unroll
    for (int off = 32; off; off >>= 1) s += __shfl_xor(s, off, 64);
    __shared__ float wsum[4];
    if ((threadIdx.x & 63) == 0) wsum[threadIdx.x >> 6] = s;
    __syncthreads();
    if (threadIdx.x == 0) out[0] = (wsum[0] + wsum[1] + wsum[2] + wsum[3]) * inv_denom;
}

extern "C" void kernel_launch(void* const* d_in, const int* in_sizes, int n_in,
                              void* d_out, int out_size, void* d_ws, size_t ws_size,
                              hipStream_t stream) {
    const float* emb    = (const float*)d_in[0];
    const int*   labels = (const int*)d_in[1];
    float*       out    = (float*)d_out;

    const int n    = in_sizes[1];                 // 8192
    const int nt   = n / 64;                      // 128 tiles per dim (64x64 tiles)
    const int ntri = nt * (nt + 1) / 2;           // 8256 triangular tiles
    const int nwaves  = (ntri + TPW - 1) / TPW;   // 2064
    const int nblocks = (nwaves + 3) / 4;         // 516
    const int npart   = nblocks * 4;

    unsigned int* en_packed = (unsigned int*)d_ws;                 // n*DIM bf16 = 2 MB
    short*        en        = (short*)d_ws;
    float*        partials  = (float*)((char*)d_ws + (size_t)n * DIM * 2);

    norm_bf16_kernel<<<n / 4, 256, 0, stream>>>(emb, en_packed);

    tri_loss_kernel<<<nblocks, 256, 0, stream>>>(en, labels, partials, nt, ntri);

    const float inv_denom = (float)(1.0 / ((double)n * (double)(n - 1)));
    final_reduce_kernel<<<1, 256, 0, stream>>>(partials, out, npart, inv_denom);
}

// Round 5
// 35.270 us; speedup vs baseline: 1.4860x; 1.4860x over previous
//
#include <hip/hip_runtime.h>
#include <hip/hip_bf16.h>

// PseudoTripletLoss on MI355X (gfx950)
// loss = sum_{i<j} [ same(i,j) ? relu(1 - cos_ij) : relu(cos_ij - 0.1) ] / (n(n-1))
//
// K1: row-normalize fp32 embeddings -> bf16 `en` in d_ws (one wave per row)
// K2: 544 exact triangular (strip, chunk-of-4) blocks. Per block:
//     - stage A tile (128x128 bf16) AND first B tile into LDS via
//       global_load_lds (fully coalesced, XOR-swizzled source columns)
//     - extract A fragments to registers once (ds_read_b128, swizzled)
//     - loop over <=4 column tiles: double-buffered B staging (reuses the A
//       buffer), per-ks ds_read of B frags -> 64 MFMA, fused hinge epilogue.
//     One barrier per tile; all global traffic is full-line coalesced.
// K3: deterministic single-block reduction of partials -> d_out[0]

typedef __attribute__((ext_vector_type(8))) short short8;
typedef __attribute__((ext_vector_type(4))) float f32x4;

#define DIM 128
#define MARGIN 0.1f
#define CHUNK 4

typedef const void __attribute__((address_space(1)))* gas_ptr;
typedef void __attribute__((address_space(3)))* las_ptr;

static __device__ __forceinline__ void load16_to_lds(const void* g, void* l) {
    __builtin_amdgcn_global_load_lds((gas_ptr)g, (las_ptr)l, 16, 0, 0);
}

static __device__ __forceinline__ unsigned short f2bf(float f) {
    unsigned int u = __builtin_bit_cast(unsigned int, f);
    u += 0x7FFFu + ((u >> 16) & 1u);   // round-to-nearest-even
    return (unsigned short)(u >> 16);
}

// Stage a 128x128 bf16 tile (rows [row0, row0+128) of en) into LDS.
// Physical 16B-slot s of row r holds logical slot s^(r&7)  (XOR involution,
// applied on the *source* column so the LDS destination stays linear —
// required by global_load_lds). Fully coalesced: each wave covers 4 rows
// x 256B contiguous (permuted within each row's 256B).
static __device__ __forceinline__ void stage_tile(const short* __restrict__ en, int row0,
                                                  short* buf, int tid) {
    const char* src = (const char*)(en + (size_t)row0 * DIM);
    char* dst = (char*)buf;
    const int r_lo = tid >> 4;       // 0..15
    const int s    = tid & 15;       // 16B slot
    #pragma unroll
    for (int p = 0; p < 8; ++p) {
        const int r  = p * 16 + r_lo;
        const int sc = (s ^ (r & 7)) << 4;
        load16_to_lds(src + (size_t)r * 256 + sc, dst + r * 256 + s * 16);
    }
}

// Read one MFMA fragment (16B) from a swizzled LDS tile.
static __device__ __forceinline__ short8 read_frag(const short* buf, int row, int slot) {
    const int ps = slot ^ (row & 7);
    return *(const short8*)(buf + row * DIM + ps * 8);
}

// ---------------- K1: normalize rows, write packed bf16 ----------------
__global__ void __launch_bounds__(256) norm_bf16_kernel(const float* __restrict__ e,
                                                        unsigned int* __restrict__ en_packed) {
    const int row  = blockIdx.x * 4 + (threadIdx.x >> 6);  // one wave per row
    const int lane = threadIdx.x & 63;
    const float2 v = *reinterpret_cast<const float2*>(e + row * DIM + lane * 2);
    float s = v.x * v.x + v.y * v.y;
    #pragma unroll
    for (int off = 32; off; off >>= 1) s += __shfl_xor(s, off, 64);
    const float scale = 1.0f / fmaxf(sqrtf(s), 1e-8f);
    const unsigned int lo = f2bf(v.x * scale);
    const unsigned int hi = f2bf(v.y * scale);
    en_packed[row * (DIM / 2) + lane] = (hi << 16) | lo;
}

// ---------------- K2: LDS-staged triangular tile GEMM + fused hinge loss ----------------
__global__ void __launch_bounds__(256, 2)
tri_loss_kernel(const short* __restrict__ en, const int* __restrict__ labels,
                float* __restrict__ partials, int nt) {
    __shared__ __align__(16) short buf[2][128 * DIM];   // 2 x 32 KB
    __shared__ float wsum[4];

    // ---- exact (strip bi, chunk t) decode: no dead blocks ----
    int t  = blockIdx.x;
    int bi = 0, cnt = (nt + CHUNK - 1) / CHUNK;
    #pragma unroll 1
    while (t >= cnt) { t -= cnt; ++bi; cnt = (nt - bi + CHUNK - 1) / CHUNK; }
    const int jbase = bi + t * CHUNK;
    const int ntile = min(CHUNK, nt - jbase);

    const int tid  = threadIdx.x;
    const int lane = tid & 63;
    const int wid  = tid >> 6;          // 4 waves = 2x2 quadrants of 128x128
    const int wr   = wid >> 1, wc = wid & 1;
    const int lm   = lane & 15;
    const int hi   = lane >> 4;

    // ---- prologue: stage A tile and first B tile (both coalesced) ----
    stage_tile(en, bi * 128, &buf[0][0], tid);
    stage_tile(en, jbase * 128, &buf[1][0], tid);

    // row labels (tiny, broadcast within 16-lane groups)
    const int r0 = bi * 128 + wr * 64;
    int4 li[4];
    #pragma unroll
    for (int m = 0; m < 4; ++m) li[m] = *(const int4*)(labels + r0 + m * 16 + hi * 4);

    __syncthreads();                    // both stages complete (vmcnt drained)

    // ---- extract A fragments to registers (held across all tiles) ----
    short8 a[4][4];
    #pragma unroll
    for (int m = 0; m < 4; ++m)
        #pragma unroll
        for (int ks = 0; ks < 4; ++ks)
            a[m][ks] = read_frag(&buf[0][0], wr * 64 + m * 16 + lm, hi + ks * 4);

    __syncthreads();                    // A reads done -> buf0 reusable for B

    float lsum0 = 0.0f, lsum1 = 0.0f;
    const int rb = hi * 4;

    #pragma unroll 1
    for (int tt = 0; tt < ntile; ++tt) {
        const short* cur = &buf[(tt & 1) ^ 1][0];        // B(tt) lives here
        if (tt + 1 < ntile)                               // prefetch B(tt+1)
            stage_tile(en, (jbase + tt + 1) * 128, &buf[tt & 1][0], tid);

        const int bj = jbase + tt;
        const int c0 = bj * 128 + wc * 64;
        int labj[4];
        #pragma unroll
        for (int n = 0; n < 4; ++n) labj[n] = labels[c0 + n * 16 + lm];

        f32x4 acc[4][4] = {};
        #pragma unroll
        for (int ks = 0; ks < 4; ++ks) {
            short8 b[4];
            #pragma unroll
            for (int n = 0; n < 4; ++n)
                b[n] = read_frag(cur, wc * 64 + n * 16 + lm, hi + ks * 4);
            #pragma unroll
            for (int m = 0; m < 4; ++m)
                #pragma unroll
                for (int n = 0; n < 4; ++n)
                    acc[m][n] = __builtin_amdgcn_mfma_f32_16x16x32_bf16(a[m][ks], b[n], acc[m][n], 0, 0, 0);
        }

        // ---- fused hinge epilogue (C/D map: col = lane&15, row = hi*4 + reg) ----
        const bool diag = (bj == bi);
        #pragma unroll
        for (int m = 0; m < 4; ++m) {
            #pragma unroll
            for (int r = 0; r < 4; ++r) {
                const int i   = r0 + m * 16 + rb + r;
                const int l_i = ((const int*)&li[m])[r];
                #pragma unroll
                for (int n = 0; n < 4; ++n) {
                    const int j  = c0 + n * 16 + lm;
                    const float s  = acc[m][n][r];
                    const float t2 = (l_i == labj[n]) ? (1.0f - s) : (s - MARGIN);
                    const float v  = fmaxf(t2, 0.0f);
                    if (!diag || i < j) { if (n & 1) lsum1 += v; else lsum0 += v; }
                }
            }
        }
        __syncthreads();   // tile reads done; next stage landed (vmcnt drain)
    }

    float lsum = lsum0 + lsum1;
    #pragma unroll
    for (int off = 32; off; off >>= 1) lsum += __shfl_down(lsum, off, 64);
    if (lane == 0) wsum[wid] = lsum;
    __syncthreads();
    if (tid == 0) partials[blockIdx.x] = wsum[0] + wsum[1] + wsum[2] + wsum[3];
}

// ---------------- K3: final deterministic reduce ----------------
__global__ void __launch_bounds__(256) final_reduce_kernel(const float* __restrict__ partials,
                                                           float* __restrict__ out,
                                                           int n, float inv_denom) {
    float s = 0.0f;
    for (int i = threadIdx.x; i < n; i += 256) s += partials[i];
    #pragma unroll
    for (int off = 32; off; off >>= 1) s += __shfl_xor(s, off, 64);
    __shared__ float wsum[4];
    if ((threadIdx.x & 63) == 0) wsum[threadIdx.x >> 6] = s;
    __syncthreads();
    if (threadIdx.x == 0) out[0] = (wsum[0] + wsum[1] + wsum[2] + wsum[3]) * inv_denom;
}

extern "C" void kernel_launch(void* const* d_in, const int* in_sizes, int n_in,
                              void* d_out, int out_size, void* d_ws, size_t ws_size,
                              hipStream_t stream) {
    const float* emb    = (const float*)d_in[0];
    const int*   labels = (const int*)d_in[1];
    float*       out    = (float*)d_out;

    const int n  = in_sizes[1];      // 8192
    const int nt = n / 128;          // 64 tiles per dim

    int Tc = 0;                      // exact number of (strip, chunk) blocks = 544
    for (int i = 0; i < nt; ++i) Tc += (nt - i + CHUNK - 1) / CHUNK;

    unsigned int* en_packed = (unsigned int*)d_ws;                 // n*DIM bf16 = 2 MB
    short*        en        = (short*)d_ws;
    float*        partials  = (float*)((char*)d_ws + (size_t)n * DIM * 2);  // Tc floats

    norm_bf16_kernel<<<n / 4, 256, 0, stream>>>(emb, en_packed);

    tri_loss_kernel<<<Tc, 256, 0, stream>>>(en, labels, partials, nt);

    const float inv_denom = (float)(1.0 / ((double)n * (double)(n - 1)));
    final_reduce_kernel<<<1, 256, 0, stream>>>(partials, out, Tc, inv_denom);
}

// Round 6
// 30.997 us; speedup vs baseline: 1.6909x; 1.1379x over previous
//
#include <hip/hip_runtime.h>
#include <hip/hip_bf16.h>

// PseudoTripletLoss on MI355X (gfx950)
// loss = sum_{i<j} [ same(i,j) ? relu(1 - cos_ij) : relu(cos_ij - 0.1) ] / (n(n-1))
//
// K1: row-normalize fp32 embeddings -> bf16 `en` in d_ws (one wave per row)
// K2: 544 exact triangular (128-row strip, chunk of 512 cols) blocks.
//     B staged as 64x128 subtiles (16 KB, double-buffered) -> 32 KB LDS/block,
//     __launch_bounds__(256,3) -> 3 blocks/CU, one wave per block per SIMD ->
//     independently-phased waves overlap MFMA / epilogue-VALU / staging.
//     A strip bounced LDS->regs once (coalesced), buffers recycled for B.
//     XOR-swizzled stage/read involution keeps ds_read_b128 conflict-free.
// K3: deterministic single-block reduction of partials -> d_out[0]

typedef __attribute__((ext_vector_type(8))) short short8;
typedef __attribute__((ext_vector_type(4))) float f32x4;

#define DIM 128
#define MARGIN 0.1f
#define CHUNK 4      // 128-col tiles per block -> 8 subtiles of 64 cols

typedef const void __attribute__((address_space(1)))* gas_ptr;
typedef void __attribute__((address_space(3)))* las_ptr;

static __device__ __forceinline__ void load16_to_lds(const void* g, void* l) {
    __builtin_amdgcn_global_load_lds((gas_ptr)g, (las_ptr)l, 16, 0, 0);
}

static __device__ __forceinline__ unsigned short f2bf(float f) {
    unsigned int u = __builtin_bit_cast(unsigned int, f);
    u += 0x7FFFu + ((u >> 16) & 1u);   // round-to-nearest-even
    return (unsigned short)(u >> 16);
}

// Stage a 64x128 bf16 tile (rows [row0,row0+64) of en) into a 16 KB LDS buf.
// XOR involution on the SOURCE column (LDS dest stays lane-linear as
// global_load_lds requires: per-wave dst = base + lane*16).
static __device__ __forceinline__ void stage64(const short* __restrict__ en, int row0,
                                               short* buf, int tid) {
    const char* src = (const char*)(en + (size_t)row0 * DIM);
    char* dst = (char*)buf;
    const int r_lo = tid >> 4;       // 0..15
    const int s    = tid & 15;       // 16B slot
    #pragma unroll
    for (int p = 0; p < 4; ++p) {
        const int r  = p * 16 + r_lo;
        const int sc = (s ^ (r & 7)) << 4;
        load16_to_lds(src + (size_t)r * 256 + sc, dst + r * 256 + s * 16);
    }
}

// Read one MFMA fragment (16B) from a swizzled LDS tile.
static __device__ __forceinline__ short8 read_frag(const short* buf, int row, int slot) {
    const int ps = slot ^ (row & 7);
    return *(const short8*)(buf + row * DIM + ps * 8);
}

// ---------------- K1: normalize rows, write packed bf16 ----------------
__global__ void __launch_bounds__(256) norm_bf16_kernel(const float* __restrict__ e,
                                                        unsigned int* __restrict__ en_packed) {
    const int row  = blockIdx.x * 4 + (threadIdx.x >> 6);  // one wave per row
    const int lane = threadIdx.x & 63;
    const float2 v = *reinterpret_cast<const float2*>(e + row * DIM + lane * 2);
    float s = v.x * v.x + v.y * v.y;
    #pragma unroll
    for (int off = 32; off; off >>= 1) s += __shfl_xor(s, off, 64);
    const float scale = 1.0f / fmaxf(sqrtf(s), 1e-8f);
    const unsigned int lo = f2bf(v.x * scale);
    const unsigned int hi = f2bf(v.y * scale);
    en_packed[row * (DIM / 2) + lane] = (hi << 16) | lo;
}

// ---------------- K2: LDS-staged triangular subtile GEMM + fused hinge loss ----------------
__global__ void __launch_bounds__(256, 3)
tri_loss_kernel(const short* __restrict__ en, const int* __restrict__ labels,
                float* __restrict__ partials, int nt) {
    __shared__ __align__(16) short buf[2][64 * DIM];   // 2 x 16 KB
    __shared__ float wsum[4];

    // ---- exact (strip bi, chunk t) decode: no dead blocks ----
    int t  = blockIdx.x;
    int bi = 0, cnt = (nt + CHUNK - 1) / CHUNK;
    #pragma unroll 1
    while (t >= cnt) { t -= cnt; ++bi; cnt = (nt - bi + CHUNK - 1) / CHUNK; }
    const int jbase = bi + t * CHUNK;                 // in 128-col units
    const int nsub  = 2 * min(CHUNK, nt - jbase);     // 64-col subtiles

    const int tid  = threadIdx.x;
    const int lane = tid & 63;
    const int wid  = tid >> 6;          // 4 waves = 2x2 over (128 rows x 64 cols)
    const int wr   = wid >> 1, wc = wid & 1;
    const int lm   = lane & 15;
    const int hi   = lane >> 4;

    // ---- stage A strip (two 64-row halves) ----
    stage64(en, bi * 128,      &buf[0][0], tid);
    stage64(en, bi * 128 + 64, &buf[1][0], tid);

    // row labels for this wave's 64 rows
    const int r0w = bi * 128 + wr * 64;
    int4 li[4];
    #pragma unroll
    for (int m = 0; m < 4; ++m) li[m] = *(const int4*)(labels + r0w + m * 16 + hi * 4);

    __syncthreads();                    // A staged

    // ---- extract A fragments (wave's 64 rows, full K=128) ----
    short8 a[4][4];
    const short* Abuf = &buf[wr][0];
    #pragma unroll
    for (int m = 0; m < 4; ++m)
        #pragma unroll
        for (int ks = 0; ks < 4; ++ks)
            a[m][ks] = read_frag(Abuf, m * 16 + lm, hi + ks * 4);

    __syncthreads();                    // A reads done -> bufs reusable

    stage64(en, jbase * 128, &buf[0][0], tid);   // first B subtile
    __syncthreads();                    // B0 staged

    float lsum = 0.0f;
    const int rb = hi * 4;

    #pragma unroll 1
    for (int s = 0; s < nsub; ++s) {
        const short* cur = &buf[s & 1][0];
        if (s + 1 < nsub)                              // prefetch next subtile
            stage64(en, jbase * 128 + (s + 1) * 64, &buf[(s + 1) & 1][0], tid);

        const int c0 = jbase * 128 + s * 64 + wc * 32;
        int labj[2];
        labj[0] = labels[c0 + lm];
        labj[1] = labels[c0 + 16 + lm];

        f32x4 acc[4][2] = {};
        #pragma unroll
        for (int ks = 0; ks < 4; ++ks) {
            short8 b[2];
            b[0] = read_frag(cur, wc * 32 + lm,      hi + ks * 4);
            b[1] = read_frag(cur, wc * 32 + 16 + lm, hi + ks * 4);
            #pragma unroll
            for (int m = 0; m < 4; ++m)
                #pragma unroll
                for (int n = 0; n < 2; ++n)
                    acc[m][n] = __builtin_amdgcn_mfma_f32_16x16x32_bf16(a[m][ks], b[n], acc[m][n], 0, 0, 0);
        }

        // ---- fused hinge epilogue (C/D map: col = lane&15, row = hi*4 + reg) ----
        const bool diag = (jbase == bi) && (s < 2);    // subtile crosses diagonal
        #pragma unroll
        for (int m = 0; m < 4; ++m) {
            #pragma unroll
            for (int r = 0; r < 4; ++r) {
                const int i   = r0w + m * 16 + rb + r;
                const int l_i = ((const int*)&li[m])[r];
                #pragma unroll
                for (int n = 0; n < 2; ++n) {
                    const int j  = c0 + n * 16 + lm;
                    const float sv = acc[m][n][r];
                    const float t2 = (l_i == labj[n]) ? (1.0f - sv) : (sv - MARGIN);
                    const float v  = fmaxf(t2, 0.0f);
                    if (!diag || i < j) lsum += v;
                }
            }
        }
        __syncthreads();   // subtile reads done; next stage landed
    }

    #pragma unroll
    for (int off = 32; off; off >>= 1) lsum += __shfl_down(lsum, off, 64);
    if (lane == 0) wsum[wid] = lsum;
    __syncthreads();
    if (tid == 0) partials[blockIdx.x] = wsum[0] + wsum[1] + wsum[2] + wsum[3];
}

// ---------------- K3: final deterministic reduce ----------------
__global__ void __launch_bounds__(256) final_reduce_kernel(const float* __restrict__ partials,
                                                           float* __restrict__ out,
                                                           int n, float inv_denom) {
    float s = 0.0f;
    for (int i = threadIdx.x; i < n; i += 256) s += partials[i];
    #pragma unroll
    for (int off = 32; off; off >>= 1) s += __shfl_xor(s, off, 64);
    __shared__ float wsum[4];
    if ((threadIdx.x & 63) == 0) wsum[threadIdx.x >> 6] = s;
    __syncthreads();
    if (threadIdx.x == 0) out[0] = (wsum[0] + wsum[1] + wsum[2] + wsum[3]) * inv_denom;
}

extern "C" void kernel_launch(void* const* d_in, const int* in_sizes, int n_in,
                              void* d_out, int out_size, void* d_ws, size_t ws_size,
                              hipStream_t stream) {
    const float* emb    = (const float*)d_in[0];
    const int*   labels = (const int*)d_in[1];
    float*       out    = (float*)d_out;

    const int n  = in_sizes[1];      // 8192
    const int nt = n / 128;          // 64 strips

    int Tc = 0;                      // exact number of (strip, chunk) blocks = 544
    for (int i = 0; i < nt; ++i) Tc += (nt - i + CHUNK - 1) / CHUNK;

    unsigned int* en_packed = (unsigned int*)d_ws;                 // n*DIM bf16 = 2 MB
    short*        en        = (short*)d_ws;
    float*        partials  = (float*)((char*)d_ws + (size_t)n * DIM * 2);  // Tc floats

    norm_bf16_kernel<<<n / 4, 256, 0, stream>>>(emb, en_packed);

    tri_loss_kernel<<<Tc, 256, 0, stream>>>(en, labels, partials, nt);

    const float inv_denom = (float)(1.0 / ((double)n * (double)(n - 1)));
    final_reduce_kernel<<<1, 256, 0, stream>>>(partials, out, Tc, inv_denom);
}